// Round 5
// baseline (1618.494 us; speedup 1.0000x reference)
//
#include <hip/hip_runtime.h>
#include <hip/hip_bf16.h>
#include <cstdint>
#include <cstddef>

#define D_NODE 128
#define D_EDGE 64
#define D_HID  128

__device__ __forceinline__ float silu_f(float x) {
  // x * sigmoid(x); v_rcp_f32 is ~1ulp, far inside the 7.4e-2 absmax budget
  return x * __builtin_amdgcn_rcpf(1.f + __expf(-x));
}

// ---------------- edge MLP: out = silu(silu(x@W1+b1)@W2+b2) ----------------
// One thread per edge. h[128] and o[64] live in registers; W1/W2 rows are
// wave-uniform -> scalar loads (s_load), broadcast to all lanes.
__global__ __launch_bounds__(256, 1) void edge_mlp_kernel(
    const float* __restrict__ ef, const float* __restrict__ W1,
    const float* __restrict__ b1, const float* __restrict__ W2,
    const float* __restrict__ b2, float* __restrict__ out, int E) {
  const int e = blockIdx.x * 256 + threadIdx.x;
  if (e >= E) return;
  const float* __restrict__ xp = ef + (size_t)e * D_EDGE;

  float h[D_HID];
#pragma unroll
  for (int j = 0; j < D_HID; ++j) h[j] = b1[j];

  // phase 1: k rolled (x streamed through L1, one dword/lane/iter), j unrolled
  for (int k = 0; k < D_EDGE; ++k) {
    const float xk = xp[k];
    const float* __restrict__ w = W1 + (k << 7);
#pragma unroll
    for (int j = 0; j < D_HID; ++j) h[j] = fmaf(xk, w[j], h[j]);
  }
#pragma unroll
  for (int j = 0; j < D_HID; ++j) h[j] = silu_f(h[j]);

  float o[D_EDGE];
#pragma unroll
  for (int t = 0; t < D_EDGE; ++t) o[t] = b2[t];

  // phase 2: must fully unroll j (h is a register array)
#pragma unroll
  for (int j = 0; j < D_HID; ++j) {
    const float hj = h[j];
    const float* __restrict__ w = W2 + (j << 6);
#pragma unroll
    for (int t = 0; t < D_EDGE; ++t) o[t] = fmaf(hj, w[t], o[t]);
  }

  float* __restrict__ op = out + (size_t)e * D_EDGE;
#pragma unroll
  for (int t = 0; t < D_EDGE; t += 4) {
    float4 v;
    v.x = silu_f(o[t]);     v.y = silu_f(o[t + 1]);
    v.z = silu_f(o[t + 2]); v.w = silu_f(o[t + 3]);
    *reinterpret_cast<float4*>(op + t) = v;
  }
}

// ---------------- QKV projection: Q/K/V = node_feat @ Wq/Wk/Wv -------------
// Block = 256 (4 waves), 8 nodes per wave (amortize weight traffic 8x).
// Lane owns output cols {lane, lane+64}; x broadcast from LDS.
__global__ __launch_bounds__(256) void qkv_kernel(
    const float* __restrict__ nf, const float* __restrict__ Wq,
    const float* __restrict__ Wk, const float* __restrict__ Wv,
    float* __restrict__ Q, float* __restrict__ K, float* __restrict__ V, int N) {
  __shared__ float xs[32][D_NODE];
  const int tid = threadIdx.x;
  const int node0 = blockIdx.x * 32;
  const int nrows = min(32, N - node0);
  for (int i = tid; i < nrows * 32; i += 256) {  // 32 float4 per row
    const int r = i >> 5, c = (i & 31) * 4;
    float4 v = *reinterpret_cast<const float4*>(nf + (size_t)(node0 + r) * D_NODE + c);
    xs[r][c] = v.x; xs[r][c + 1] = v.y; xs[r][c + 2] = v.z; xs[r][c + 3] = v.w;
  }
  __syncthreads();
  const int wave = tid >> 6, lane = tid & 63;
  const int nn0 = wave * 8;
  float aq[8][2] = {}, ak[8][2] = {}, av[8][2] = {};
  for (int k = 0; k < D_NODE; ++k) {
    const float wq0 = Wq[(k << 7) + lane], wq1 = Wq[(k << 7) + 64 + lane];
    const float wk0 = Wk[(k << 7) + lane], wk1 = Wk[(k << 7) + 64 + lane];
    const float wv0 = Wv[(k << 7) + lane], wv1 = Wv[(k << 7) + 64 + lane];
#pragma unroll
    for (int nn = 0; nn < 8; ++nn) {
      const float x = xs[nn0 + nn][k];
      aq[nn][0] = fmaf(x, wq0, aq[nn][0]); aq[nn][1] = fmaf(x, wq1, aq[nn][1]);
      ak[nn][0] = fmaf(x, wk0, ak[nn][0]); ak[nn][1] = fmaf(x, wk1, ak[nn][1]);
      av[nn][0] = fmaf(x, wv0, av[nn][0]); av[nn][1] = fmaf(x, wv1, av[nn][1]);
    }
  }
#pragma unroll
  for (int nn = 0; nn < 8; ++nn) {
    const int n = node0 + nn0 + nn;
    if (n < N) {
      Q[(size_t)n * 128 + lane] = aq[nn][0]; Q[(size_t)n * 128 + 64 + lane] = aq[nn][1];
      K[(size_t)n * 128 + lane] = ak[nn][0]; K[(size_t)n * 128 + 64 + lane] = ak[nn][1];
      V[(size_t)n * 128 + lane] = av[nn][0]; V[(size_t)n * 128 + 64 + lane] = av[nn][1];
    }
  }
}

// ---------------- CSR build: count -> scan -> scatter ----------------------
__global__ void count_edges(const int* __restrict__ dst, int* __restrict__ counts, int E) {
  const int e = blockIdx.x * blockDim.x + threadIdx.x;
  if (e < E) atomicAdd(&counts[dst[e]], 1);
}

__global__ __launch_bounds__(1024) void scan_offsets(
    const int* __restrict__ counts, int* __restrict__ offsets, int n) {
  __shared__ int tmp[1024];
  __shared__ int carry_s;
  const int tid = threadIdx.x;
  if (tid == 0) { carry_s = 0; offsets[0] = 0; }
  __syncthreads();
  for (int base = 0; base < n; base += 1024) {
    const int i = base + tid;
    tmp[tid] = (i < n) ? counts[i] : 0;
    __syncthreads();
    for (int off = 1; off < 1024; off <<= 1) {  // Hillis-Steele inclusive scan
      const int t = (tid >= off) ? tmp[tid - off] : 0;
      __syncthreads();
      tmp[tid] += t;
      __syncthreads();
    }
    const int carry = carry_s;
    if (i < n) offsets[i + 1] = carry + tmp[tid];
    __syncthreads();
    if (tid == 1023) carry_s = carry + tmp[1023];
    __syncthreads();
  }
}

__global__ void scatter_edges(const int* __restrict__ dst, const int* __restrict__ offsets,
                              int* __restrict__ cursor, int* __restrict__ eidx, int E) {
  const int e = blockIdx.x * blockDim.x + threadIdx.x;
  if (e >= E) return;
  const int d = dst[e];
  const int pos = atomicAdd(&cursor[d], 1);
  eidx[offsets[d] + pos] = e;
}

// ---------------- fused per-node attention (online softmax) ----------------
// One wave per node; lane owns feature pair {2*lane, 2*lane+1}. Per incoming
// edge: gather K/V rows (coalesced 512B), dot via shuffle-reduce, online
// max/sum rescale. No atomics, no score array, single pass.
__global__ __launch_bounds__(256) void node_attn_kernel(
    const float* __restrict__ Q, const float* __restrict__ K, const float* __restrict__ V,
    const int* __restrict__ offsets, const int* __restrict__ eidx,
    const int* __restrict__ src, float* __restrict__ out, int N) {
  const int lane = threadIdx.x & 63;
  const int n = (blockIdx.x * blockDim.x + threadIdx.x) >> 6;
  if (n >= N) return;
  const int beg = offsets[n], end = offsets[n + 1];
  const float2 q = *reinterpret_cast<const float2*>(Q + (size_t)n * 128 + lane * 2);
  float m = -3.4e38f, l = 0.f, ax = 0.f, ay = 0.f;
  for (int p = beg; p < end; ++p) {
    const int e = eidx[p];   // wave-uniform -> scalar load
    const int s = src[e];    // wave-uniform -> scalar load
    const float2 kr = *reinterpret_cast<const float2*>(K + (size_t)s * 128 + lane * 2);
    float part = q.x * kr.x + q.y * kr.y;
#pragma unroll
    for (int off = 32; off > 0; off >>= 1) part += __shfl_xor(part, off);
    const float score = part * 0.088388347648318447f;  // 1/sqrt(128)
    const float mnew = fmaxf(m, score);
    const float corr = __expf(m - mnew);
    const float pe = __expf(score - mnew);
    const float2 vr = *reinterpret_cast<const float2*>(V + (size_t)s * 128 + lane * 2);
    l = l * corr + pe;
    ax = ax * corr + pe * vr.x;
    ay = ay * corr + pe * vr.y;
    m = mnew;
  }
  const float inv = (end > beg) ? 1.f / l : 0.f;
  float2 o; o.x = ax * inv; o.y = ay * inv;
  *reinterpret_cast<float2*>(out + (size_t)n * 128 + lane * 2) = o;
}

// ---------------------------------------------------------------------------
extern "C" void kernel_launch(void* const* d_in, const int* in_sizes, int n_in,
                              void* d_out, int out_size, void* d_ws, size_t ws_size,
                              hipStream_t stream) {
  const float* edge_feat = (const float*)d_in[0];
  const float* node_feat = (const float*)d_in[1];
  const int*   src       = (const int*)d_in[2];
  const int*   dst       = (const int*)d_in[3];
  const float* Wq        = (const float*)d_in[4];
  const float* Wk        = (const float*)d_in[5];
  const float* Wv        = (const float*)d_in[6];
  const float* W1        = (const float*)d_in[7];
  const float* b1        = (const float*)d_in[8];
  const float* W2        = (const float*)d_in[9];
  const float* b2        = (const float*)d_in[10];

  const int E = in_sizes[2];            // 800000
  const int N = in_sizes[1] / D_NODE;   // 50000

  float* edge_out = (float*)d_out;
  float* node_out = (float*)d_out + (size_t)E * D_EDGE;

  // workspace layout (256B aligned regions)
  char* w = (char*)d_ws;
  auto alloc = [&](size_t bytes) {
    char* p = w;
    w += (bytes + 255) & ~(size_t)255;
    return p;
  };
  float* Q    = (float*)alloc((size_t)N * 128 * sizeof(float));
  float* Km   = (float*)alloc((size_t)N * 128 * sizeof(float));
  float* Vm   = (float*)alloc((size_t)N * 128 * sizeof(float));
  int* counts = (int*)alloc((size_t)N * sizeof(int));
  int* cursor = (int*)alloc((size_t)N * sizeof(int));
  int* offs   = (int*)alloc((size_t)(N + 1) * sizeof(int));
  int* eidx   = (int*)alloc((size_t)E * sizeof(int));

  // counts and cursor are adjacent 256B-aligned regions: zero both in one shot
  hipMemsetAsync(counts, 0, (size_t)((char*)offs - (char*)counts), stream);

  count_edges<<<(E + 255) / 256, 256, 0, stream>>>(dst, counts, E);
  scan_offsets<<<1, 1024, 0, stream>>>(counts, offs, N);
  scatter_edges<<<(E + 255) / 256, 256, 0, stream>>>(dst, offs, cursor, eidx, E);
  qkv_kernel<<<(N + 31) / 32, 256, 0, stream>>>(node_feat, Wq, Wk, Wv, Q, Km, Vm, N);
  edge_mlp_kernel<<<(E + 255) / 256, 256, 0, stream>>>(edge_feat, W1, b1, W2, b2, edge_out, E);
  node_attn_kernel<<<(N + 3) / 4, 256, 0, stream>>>(Q, Km, Vm, offs, eidx, src, node_out, N);
}

// Round 6
// 882.738 us; speedup vs baseline: 1.8335x; 1.8335x over previous
//
#include <hip/hip_runtime.h>
#include <hip/hip_bf16.h>
#include <cstdint>
#include <cstddef>

#define D_NODE 128
#define D_EDGE 64
#define D_HID  128

typedef __attribute__((ext_vector_type(8))) short bf16x8;
typedef __attribute__((ext_vector_type(4))) float f32x4;
typedef __attribute__((ext_vector_type(4))) short short4v;

__device__ __forceinline__ float silu_f(float x) {
  return x * __builtin_amdgcn_rcpf(1.f + __expf(-x));
}

__device__ __forceinline__ short f2bf(float f) {
  union { float f; uint32_t u; } v; v.f = f;
  uint32_t r = v.u + 0x7fff + ((v.u >> 16) & 1);  // RNE
  return (short)(r >> 16);
}

// ------------- prep: W1[64,128] -> W1t bf16 [n=128][k=64]; W2[128,64] -> W2t bf16 [n=64][k=128]
__global__ void prep_weights(const float* __restrict__ W1, const float* __restrict__ W2,
                             short* __restrict__ W1t, short* __restrict__ W2t) {
  const int idx = blockIdx.x * 256 + threadIdx.x;
  if (idx < 8192) {
    const int n1 = idx >> 6, k1 = idx & 63;    // W1t[n1][k1] = W1[k1][n1]
    W1t[idx] = f2bf(W1[k1 * 128 + n1]);
    const int n2 = idx >> 7, k2 = idx & 127;   // W2t[n2][k2] = W2[k2][n2]
    W2t[idx] = f2bf(W2[k2 * 64 + n2]);
  }
}

// ------------- edge MLP via MFMA: out = silu(silu(X@W1+b1)@W2+b2) ----------
// Block: 256 thr (4 waves) x 128 edges. GEMM1 M128 N128 K64; GEMM2 M128 N64 K128.
// LDS: region{X[128][72] + W1t[128][72]} reused as H[128][136]; W2t[64][136].
__global__ __launch_bounds__(256) void edge_mlp_mfma(
    const float* __restrict__ ef, const short* __restrict__ W1t,
    const float* __restrict__ b1, const short* __restrict__ W2t,
    const float* __restrict__ b2, float* __restrict__ out, int E) {
  __shared__ short region[18432];      // 36864 B
  __shared__ short w2s[64 * 136];      // 17408 B
  short* Xs  = region;                 // stride 72
  short* W1s = region + 9216;          // stride 72
  short* Hs  = region;                 // stride 136 (overlays X+W1 after GEMM1)

  const int tid = threadIdx.x;
  const int e0 = blockIdx.x * 128;

  // stage X tile fp32 -> bf16 (guarded), coalesced float4
#pragma unroll
  for (int it = 0; it < 8; ++it) {
    const int i = tid + it * 256;            // 2048 float4 = 128x64
    const int row = i >> 4, col = (i & 15) * 4;
    float4 v = make_float4(0.f, 0.f, 0.f, 0.f);
    if (e0 + row < E) v = *reinterpret_cast<const float4*>(ef + (size_t)(e0 + row) * 64 + col);
    short4v s; s.x = f2bf(v.x); s.y = f2bf(v.y); s.z = f2bf(v.z); s.w = f2bf(v.w);
    *reinterpret_cast<short4v*>(&Xs[row * 72 + col]) = s;
  }
  // stage W1t [128][64]
#pragma unroll
  for (int it = 0; it < 8; ++it) {
    const int i = tid + it * 256;            // 2048 short4 = 128x64
    const int row = i >> 4, col = (i & 15) * 4;
    *reinterpret_cast<short4v*>(&W1s[row * 72 + col]) =
        *reinterpret_cast<const short4v*>(W1t + row * 64 + col);
  }
  // stage W2t [64][128]
#pragma unroll
  for (int it = 0; it < 8; ++it) {
    const int i = tid + it * 256;            // 2048 short4 = 64x128
    const int row = i >> 5, col = (i & 31) * 4;
    *reinterpret_cast<short4v*>(&w2s[row * 136 + col]) =
        *reinterpret_cast<const short4v*>(W2t + row * 128 + col);
  }

  const int lane = tid & 63, wave = tid >> 6;
  const int r0 = wave * 32;                  // 32 edge-rows per wave
  const int lr = lane & 15, lg = lane >> 4;
  float b1v[8], b2v[4];
#pragma unroll
  for (int n = 0; n < 8; ++n) b1v[n] = b1[n * 16 + lr];
#pragma unroll
  for (int n = 0; n < 4; ++n) b2v[n] = b2[n * 16 + lr];
  __syncthreads();

  // GEMM1: acc1[m][n] over K=64 (2 k-steps)
  f32x4 acc1[2][8];
#pragma unroll
  for (int m = 0; m < 2; ++m)
#pragma unroll
    for (int n = 0; n < 8; ++n) acc1[m][n] = (f32x4){0.f, 0.f, 0.f, 0.f};
#pragma unroll
  for (int kk = 0; kk < 2; ++kk) {
    const bf16x8 a0 = *reinterpret_cast<const bf16x8*>(&Xs[(r0 + lr) * 72 + kk * 32 + lg * 8]);
    const bf16x8 a1 = *reinterpret_cast<const bf16x8*>(&Xs[(r0 + 16 + lr) * 72 + kk * 32 + lg * 8]);
#pragma unroll
    for (int n = 0; n < 8; ++n) {
      const bf16x8 b = *reinterpret_cast<const bf16x8*>(&W1s[(n * 16 + lr) * 72 + kk * 32 + lg * 8]);
      acc1[0][n] = __builtin_amdgcn_mfma_f32_16x16x32_bf16(a0, b, acc1[0][n], 0, 0, 0);
      acc1[1][n] = __builtin_amdgcn_mfma_f32_16x16x32_bf16(a1, b, acc1[1][n], 0, 0, 0);
    }
  }
  __syncthreads();  // all GEMM1 LDS reads drained before overwriting region with H

  // H = silu(acc1 + b1) -> bf16 LDS (C/D layout: col=lane&15, row=lg*4+r)
#pragma unroll
  for (int m = 0; m < 2; ++m)
#pragma unroll
    for (int n = 0; n < 8; ++n)
#pragma unroll
      for (int r = 0; r < 4; ++r) {
        const float hv = silu_f(acc1[m][n][r] + b1v[n]);
        Hs[(r0 + m * 16 + lg * 4 + r) * 136 + n * 16 + lr] = f2bf(hv);
      }
  __syncthreads();

  // GEMM2: acc2[m][n] over K=128 (4 k-steps)
  f32x4 acc2[2][4];
#pragma unroll
  for (int m = 0; m < 2; ++m)
#pragma unroll
    for (int n = 0; n < 4; ++n) acc2[m][n] = (f32x4){0.f, 0.f, 0.f, 0.f};
#pragma unroll
  for (int kk = 0; kk < 4; ++kk) {
    const bf16x8 a0 = *reinterpret_cast<const bf16x8*>(&Hs[(r0 + lr) * 136 + kk * 32 + lg * 8]);
    const bf16x8 a1 = *reinterpret_cast<const bf16x8*>(&Hs[(r0 + 16 + lr) * 136 + kk * 32 + lg * 8]);
#pragma unroll
    for (int n = 0; n < 4; ++n) {
      const bf16x8 b = *reinterpret_cast<const bf16x8*>(&w2s[(n * 16 + lr) * 136 + kk * 32 + lg * 8]);
      acc2[0][n] = __builtin_amdgcn_mfma_f32_16x16x32_bf16(a0, b, acc2[0][n], 0, 0, 0);
      acc2[1][n] = __builtin_amdgcn_mfma_f32_16x16x32_bf16(a1, b, acc2[1][n], 0, 0, 0);
    }
  }
  // epilogue: silu(acc2 + b2) -> fp32 out
#pragma unroll
  for (int m = 0; m < 2; ++m)
#pragma unroll
    for (int r = 0; r < 4; ++r) {
      const int row = r0 + m * 16 + lg * 4 + r;
      if (e0 + row < E) {
        float* __restrict__ op = out + (size_t)(e0 + row) * 64;
#pragma unroll
        for (int n = 0; n < 4; ++n) op[n * 16 + lr] = silu_f(acc2[m][n][r] + b2v[n]);
      }
    }
}

// ---------------- QKV projection (unchanged) -------------------------------
__global__ __launch_bounds__(256) void qkv_kernel(
    const float* __restrict__ nf, const float* __restrict__ Wq,
    const float* __restrict__ Wk, const float* __restrict__ Wv,
    float* __restrict__ Q, float* __restrict__ K, float* __restrict__ V, int N) {
  __shared__ float xs[32][D_NODE];
  const int tid = threadIdx.x;
  const int node0 = blockIdx.x * 32;
  const int nrows = min(32, N - node0);
  for (int i = tid; i < nrows * 32; i += 256) {
    const int r = i >> 5, c = (i & 31) * 4;
    float4 v = *reinterpret_cast<const float4*>(nf + (size_t)(node0 + r) * D_NODE + c);
    xs[r][c] = v.x; xs[r][c + 1] = v.y; xs[r][c + 2] = v.z; xs[r][c + 3] = v.w;
  }
  __syncthreads();
  const int wave = tid >> 6, lane = tid & 63;
  const int nn0 = wave * 8;
  float aq[8][2] = {}, ak[8][2] = {}, av[8][2] = {};
  for (int k = 0; k < D_NODE; ++k) {
    const float wq0 = Wq[(k << 7) + lane], wq1 = Wq[(k << 7) + 64 + lane];
    const float wk0 = Wk[(k << 7) + lane], wk1 = Wk[(k << 7) + 64 + lane];
    const float wv0 = Wv[(k << 7) + lane], wv1 = Wv[(k << 7) + 64 + lane];
#pragma unroll
    for (int nn = 0; nn < 8; ++nn) {
      const float x = xs[nn0 + nn][k];
      aq[nn][0] = fmaf(x, wq0, aq[nn][0]); aq[nn][1] = fmaf(x, wq1, aq[nn][1]);
      ak[nn][0] = fmaf(x, wk0, ak[nn][0]); ak[nn][1] = fmaf(x, wk1, ak[nn][1]);
      av[nn][0] = fmaf(x, wv0, av[nn][0]); av[nn][1] = fmaf(x, wv1, av[nn][1]);
    }
  }
#pragma unroll
  for (int nn = 0; nn < 8; ++nn) {
    const int n = node0 + nn0 + nn;
    if (n < N) {
      Q[(size_t)n * 128 + lane] = aq[nn][0]; Q[(size_t)n * 128 + 64 + lane] = aq[nn][1];
      K[(size_t)n * 128 + lane] = ak[nn][0]; K[(size_t)n * 128 + 64 + lane] = ak[nn][1];
      V[(size_t)n * 128 + lane] = av[nn][0]; V[(size_t)n * 128 + 64 + lane] = av[nn][1];
    }
  }
}

// ---------------- CSR build (unchanged) ------------------------------------
__global__ void count_edges(const int* __restrict__ dst, int* __restrict__ counts, int E) {
  const int e = blockIdx.x * blockDim.x + threadIdx.x;
  if (e < E) atomicAdd(&counts[dst[e]], 1);
}

__global__ __launch_bounds__(1024) void scan_offsets(
    const int* __restrict__ counts, int* __restrict__ offsets, int n) {
  __shared__ int tmp[1024];
  __shared__ int carry_s;
  const int tid = threadIdx.x;
  if (tid == 0) { carry_s = 0; offsets[0] = 0; }
  __syncthreads();
  for (int base = 0; base < n; base += 1024) {
    const int i = base + tid;
    tmp[tid] = (i < n) ? counts[i] : 0;
    __syncthreads();
    for (int off = 1; off < 1024; off <<= 1) {
      const int t = (tid >= off) ? tmp[tid - off] : 0;
      __syncthreads();
      tmp[tid] += t;
      __syncthreads();
    }
    const int carry = carry_s;
    if (i < n) offsets[i + 1] = carry + tmp[tid];
    __syncthreads();
    if (tid == 1023) carry_s = carry + tmp[1023];
    __syncthreads();
  }
}

__global__ void scatter_edges(const int* __restrict__ dst, const int* __restrict__ offsets,
                              int* __restrict__ cursor, int* __restrict__ eidx, int E) {
  const int e = blockIdx.x * blockDim.x + threadIdx.x;
  if (e >= E) return;
  const int d = dst[e];
  const int pos = atomicAdd(&cursor[d], 1);
  eidx[offsets[d] + pos] = e;
}

// ---------------- fused per-node attention (unchanged) ---------------------
__global__ __launch_bounds__(256) void node_attn_kernel(
    const float* __restrict__ Q, const float* __restrict__ K, const float* __restrict__ V,
    const int* __restrict__ offsets, const int* __restrict__ eidx,
    const int* __restrict__ src, float* __restrict__ out, int N) {
  const int lane = threadIdx.x & 63;
  const int n = (blockIdx.x * blockDim.x + threadIdx.x) >> 6;
  if (n >= N) return;
  const int beg = offsets[n], end = offsets[n + 1];
  const float2 q = *reinterpret_cast<const float2*>(Q + (size_t)n * 128 + lane * 2);
  float m = -3.4e38f, l = 0.f, ax = 0.f, ay = 0.f;
  for (int p = beg; p < end; ++p) {
    const int e = eidx[p];
    const int s = src[e];
    const float2 kr = *reinterpret_cast<const float2*>(K + (size_t)s * 128 + lane * 2);
    float part = q.x * kr.x + q.y * kr.y;
#pragma unroll
    for (int off = 32; off > 0; off >>= 1) part += __shfl_xor(part, off);
    const float score = part * 0.088388347648318447f;  // 1/sqrt(128)
    const float mnew = fmaxf(m, score);
    const float corr = __expf(m - mnew);
    const float pe = __expf(score - mnew);
    const float2 vr = *reinterpret_cast<const float2*>(V + (size_t)s * 128 + lane * 2);
    l = l * corr + pe;
    ax = ax * corr + pe * vr.x;
    ay = ay * corr + pe * vr.y;
    m = mnew;
  }
  const float inv = (end > beg) ? 1.f / l : 0.f;
  float2 o; o.x = ax * inv; o.y = ay * inv;
  *reinterpret_cast<float2*>(out + (size_t)n * 128 + lane * 2) = o;
}

// ---------------------------------------------------------------------------
extern "C" void kernel_launch(void* const* d_in, const int* in_sizes, int n_in,
                              void* d_out, int out_size, void* d_ws, size_t ws_size,
                              hipStream_t stream) {
  const float* edge_feat = (const float*)d_in[0];
  const float* node_feat = (const float*)d_in[1];
  const int*   src       = (const int*)d_in[2];
  const int*   dst       = (const int*)d_in[3];
  const float* Wq        = (const float*)d_in[4];
  const float* Wk        = (const float*)d_in[5];
  const float* Wv        = (const float*)d_in[6];
  const float* W1        = (const float*)d_in[7];
  const float* b1        = (const float*)d_in[8];
  const float* W2        = (const float*)d_in[9];
  const float* b2        = (const float*)d_in[10];

  const int E = in_sizes[2];            // 800000
  const int N = in_sizes[1] / D_NODE;   // 50000

  float* edge_out = (float*)d_out;
  float* node_out = (float*)d_out + (size_t)E * D_EDGE;

  char* w = (char*)d_ws;
  auto alloc = [&](size_t bytes) {
    char* p = w;
    w += (bytes + 255) & ~(size_t)255;
    return p;
  };
  float* Q    = (float*)alloc((size_t)N * 128 * sizeof(float));
  float* Km   = (float*)alloc((size_t)N * 128 * sizeof(float));
  float* Vm   = (float*)alloc((size_t)N * 128 * sizeof(float));
  int* counts = (int*)alloc((size_t)N * sizeof(int));
  int* cursor = (int*)alloc((size_t)N * sizeof(int));
  int* offs   = (int*)alloc((size_t)(N + 1) * sizeof(int));
  int* eidx   = (int*)alloc((size_t)E * sizeof(int));
  short* W1t  = (short*)alloc(8192 * sizeof(short));
  short* W2t  = (short*)alloc(8192 * sizeof(short));

  hipMemsetAsync(counts, 0, (size_t)((char*)offs - (char*)counts), stream);

  prep_weights<<<32, 256, 0, stream>>>(W1, W2, W1t, W2t);
  count_edges<<<(E + 255) / 256, 256, 0, stream>>>(dst, counts, E);
  scan_offsets<<<1, 1024, 0, stream>>>(counts, offs, N);
  scatter_edges<<<(E + 255) / 256, 256, 0, stream>>>(dst, offs, cursor, eidx, E);
  qkv_kernel<<<(N + 31) / 32, 256, 0, stream>>>(node_feat, Wq, Wk, Wv, Q, Km, Vm, N);
  edge_mlp_mfma<<<(E + 127) / 128, 256, 0, stream>>>(edge_feat, W1t, b1, W2t, b2, edge_out, E);
  node_attn_kernel<<<(N + 3) / 4, 256, 0, stream>>>(Q, Km, Vm, offs, eidx, src, node_out, N);
}

// Round 8
// 769.234 us; speedup vs baseline: 2.1040x; 1.1476x over previous
//
#include <hip/hip_runtime.h>
#include <hip/hip_bf16.h>
#include <cstdint>
#include <cstddef>

#define D_NODE 128
#define D_EDGE 64
#define D_HID  128

typedef __attribute__((ext_vector_type(8))) short bf16x8;
typedef __attribute__((ext_vector_type(4))) float f32x4;

__device__ __forceinline__ float silu_f(float x) {
  return x * __builtin_amdgcn_rcpf(1.f + __expf(-x));
}

__device__ __forceinline__ short f2bf(float f) {
  union { float f; uint32_t u; } v; v.f = f;
  uint32_t r = v.u + 0x7fff + ((v.u >> 16) & 1);  // RNE
  return (short)(r >> 16);
}

// ------------- prep: repack W1/W2 into bf16 MFMA B-fragment order ----------
// W1 [64,128] -> W1f: frag(kk=0..1,n=0..7), elem = W1[kk*32+lg*8+j][n*16+lr]
//   W1f[((kk*8+n)*64 + lane)*8 + j]     (lane = lg*16+lr)
// W2 [128,64] -> W2f: frag(kk=0..3,n=0..3), elem = W2[kk*32+lg*8+j][n*16+lr]
//   W2f[((kk*4+n)*64 + lane)*8 + j]
__global__ void prep_weights(const float* __restrict__ W1, const float* __restrict__ W2,
                             short* __restrict__ W1f, short* __restrict__ W2f) {
  const int idx = blockIdx.x * 256 + threadIdx.x;   // 2048 threads
  if (idx < 1024) {
    const int frag = idx >> 6, lane = idx & 63;
    const int kk = frag >> 3, n = frag & 7;
    const int lg = lane >> 4, lr = lane & 15;
#pragma unroll
    for (int j = 0; j < 8; ++j) {
      const int k = kk * 32 + lg * 8 + j;
      W1f[idx * 8 + j] = f2bf(W1[k * 128 + n * 16 + lr]);
    }
  } else if (idx < 2048) {
    const int t = idx - 1024;
    const int frag = t >> 6, lane = t & 63;
    const int kk = frag >> 2, n = frag & 3;
    const int lg = lane >> 4, lr = lane & 15;
#pragma unroll
    for (int j = 0; j < 8; ++j) {
      const int k = kk * 32 + lg * 8 + j;
      W2f[t * 8 + j] = f2bf(W2[k * 64 + n * 16 + lr]);
    }
  }
}

// ------------- edge MLP via MFMA, zero barriers ----------------------------
// 256 thr (4 waves) x 128 edges. X + weights direct from global (no staging
// LDS); only H round-trips through LDS, and each wave reads exactly the rows
// it wrote -> no __syncthreads at all. LDS 34.8KB -> 4 blocks/CU.
__global__ __launch_bounds__(256) void edge_mlp_mfma(
    const float* __restrict__ ef, const short* __restrict__ W1f,
    const float* __restrict__ b1, const short* __restrict__ W2f,
    const float* __restrict__ b2, float* __restrict__ out, int E) {
  __shared__ short Hs[128 * 136];

  const int tid = threadIdx.x;
  const int e0 = blockIdx.x * 128;
  const int lane = tid & 63, wave = tid >> 6;
  const int r0 = wave * 32;
  const int lr = lane & 15, lg = lane >> 4;

  float b1v[8], b2v[4];
#pragma unroll
  for (int n = 0; n < 8; ++n) b1v[n] = b1[n * 16 + lr];
#pragma unroll
  for (int n = 0; n < 4; ++n) b2v[n] = b2[n * 16 + lr];

  // ---- GEMM1: [32 rows/wave x 128] = X(32x64) @ W1(64x128) ----
  f32x4 acc1[2][8];
#pragma unroll
  for (int m = 0; m < 2; ++m)
#pragma unroll
    for (int n = 0; n < 8; ++n) acc1[m][n] = (f32x4){0.f, 0.f, 0.f, 0.f};

#pragma unroll
  for (int kk = 0; kk < 2; ++kk) {
    bf16x8 a[2];
#pragma unroll
    for (int m = 0; m < 2; ++m) {
      const int row = e0 + r0 + m * 16 + lr;
      const float* __restrict__ xp = ef + (size_t)row * 64 + kk * 32 + lg * 8;
      float4 f0 = make_float4(0.f, 0.f, 0.f, 0.f), f1 = f0;
      if (row < E) {
        f0 = *reinterpret_cast<const float4*>(xp);
        f1 = *reinterpret_cast<const float4*>(xp + 4);
      }
      a[m][0] = f2bf(f0.x); a[m][1] = f2bf(f0.y); a[m][2] = f2bf(f0.z); a[m][3] = f2bf(f0.w);
      a[m][4] = f2bf(f1.x); a[m][5] = f2bf(f1.y); a[m][6] = f2bf(f1.z); a[m][7] = f2bf(f1.w);
    }
#pragma unroll
    for (int n = 0; n < 8; ++n) {
      const bf16x8 b = *reinterpret_cast<const bf16x8*>(W1f + (((kk << 3) + n) << 9) + (lane << 3));
      acc1[0][n] = __builtin_amdgcn_mfma_f32_16x16x32_bf16(a[0], b, acc1[0][n], 0, 0, 0);
      acc1[1][n] = __builtin_amdgcn_mfma_f32_16x16x32_bf16(a[1], b, acc1[1][n], 0, 0, 0);
    }
  }

  // ---- H = silu(acc1+b1) -> LDS (C/D layout: col=n*16+lr, row=lg*4+r) ----
#pragma unroll
  for (int m = 0; m < 2; ++m)
#pragma unroll
    for (int n = 0; n < 8; ++n)
#pragma unroll
      for (int r = 0; r < 4; ++r) {
        const float hv = silu_f(acc1[m][n][r] + b1v[n]);
        Hs[(r0 + m * 16 + lg * 4 + r) * 136 + n * 16 + lr] = f2bf(hv);
      }
  // no barrier: each wave reads back only rows r0..r0+31 (its own writes)

  // ---- GEMM2: [32 x 64] = H(32x128) @ W2(128x64) ----
  f32x4 acc2[2][4];
#pragma unroll
  for (int m = 0; m < 2; ++m)
#pragma unroll
    for (int n = 0; n < 4; ++n) acc2[m][n] = (f32x4){0.f, 0.f, 0.f, 0.f};
#pragma unroll
  for (int kk = 0; kk < 4; ++kk) {
    const bf16x8 a0 = *reinterpret_cast<const bf16x8*>(&Hs[(r0 + lr) * 136 + kk * 32 + lg * 8]);
    const bf16x8 a1 = *reinterpret_cast<const bf16x8*>(&Hs[(r0 + 16 + lr) * 136 + kk * 32 + lg * 8]);
#pragma unroll
    for (int n = 0; n < 4; ++n) {
      const bf16x8 b = *reinterpret_cast<const bf16x8*>(W2f + (((kk << 2) + n) << 9) + (lane << 3));
      acc2[0][n] = __builtin_amdgcn_mfma_f32_16x16x32_bf16(a0, b, acc2[0][n], 0, 0, 0);
      acc2[1][n] = __builtin_amdgcn_mfma_f32_16x16x32_bf16(a1, b, acc2[1][n], 0, 0, 0);
    }
  }
#pragma unroll
  for (int m = 0; m < 2; ++m)
#pragma unroll
    for (int r = 0; r < 4; ++r) {
      const int row = r0 + m * 16 + lg * 4 + r;
      if (e0 + row < E) {
        float* __restrict__ op = out + (size_t)(e0 + row) * 64;
#pragma unroll
        for (int n = 0; n < 4; ++n) op[n * 16 + lr] = silu_f(acc2[m][n][r] + b2v[n]);
      }
    }
}

// ---------------- QKV projection (unchanged) -------------------------------
__global__ __launch_bounds__(256) void qkv_kernel(
    const float* __restrict__ nf, const float* __restrict__ Wq,
    const float* __restrict__ Wk, const float* __restrict__ Wv,
    float* __restrict__ Q, float* __restrict__ K, float* __restrict__ V, int N) {
  __shared__ float xs[32][D_NODE];
  const int tid = threadIdx.x;
  const int node0 = blockIdx.x * 32;
  const int nrows = min(32, N - node0);
  for (int i = tid; i < nrows * 32; i += 256) {
    const int r = i >> 5, c = (i & 31) * 4;
    float4 v = *reinterpret_cast<const float4*>(nf + (size_t)(node0 + r) * D_NODE + c);
    xs[r][c] = v.x; xs[r][c + 1] = v.y; xs[r][c + 2] = v.z; xs[r][c + 3] = v.w;
  }
  __syncthreads();
  const int wave = tid >> 6, lane = tid & 63;
  const int nn0 = wave * 8;
  float aq[8][2] = {}, ak[8][2] = {}, av[8][2] = {};
  for (int k = 0; k < D_NODE; ++k) {
    const float wq0 = Wq[(k << 7) + lane], wq1 = Wq[(k << 7) + 64 + lane];
    const float wk0 = Wk[(k << 7) + lane], wk1 = Wk[(k << 7) + 64 + lane];
    const float wv0 = Wv[(k << 7) + lane], wv1 = Wv[(k << 7) + 64 + lane];
#pragma unroll
    for (int nn = 0; nn < 8; ++nn) {
      const float x = xs[nn0 + nn][k];
      aq[nn][0] = fmaf(x, wq0, aq[nn][0]); aq[nn][1] = fmaf(x, wq1, aq[nn][1]);
      ak[nn][0] = fmaf(x, wk0, ak[nn][0]); ak[nn][1] = fmaf(x, wk1, ak[nn][1]);
      av[nn][0] = fmaf(x, wv0, av[nn][0]); av[nn][1] = fmaf(x, wv1, av[nn][1]);
    }
  }
#pragma unroll
  for (int nn = 0; nn < 8; ++nn) {
    const int n = node0 + nn0 + nn;
    if (n < N) {
      Q[(size_t)n * 128 + lane] = aq[nn][0]; Q[(size_t)n * 128 + 64 + lane] = aq[nn][1];
      K[(size_t)n * 128 + lane] = ak[nn][0]; K[(size_t)n * 128 + 64 + lane] = ak[nn][1];
      V[(size_t)n * 128 + lane] = av[nn][0]; V[(size_t)n * 128 + 64 + lane] = av[nn][1];
    }
  }
}

// ---------------- CSR build ------------------------------------------------
__global__ void count_edges(const int* __restrict__ dst, int* __restrict__ counts, int E) {
  const int e = blockIdx.x * blockDim.x + threadIdx.x;
  if (e < E) atomicAdd(&counts[dst[e]], 1);
}

__global__ __launch_bounds__(1024) void scan_offsets(
    const int* __restrict__ counts, int* __restrict__ offsets, int n) {
  __shared__ int tmp[1024];
  __shared__ int carry_s;
  const int tid = threadIdx.x;
  if (tid == 0) { carry_s = 0; offsets[0] = 0; }
  __syncthreads();
  for (int base = 0; base < n; base += 1024) {
    const int i = base + tid;
    tmp[tid] = (i < n) ? counts[i] : 0;
    __syncthreads();
    for (int off = 1; off < 1024; off <<= 1) {
      const int t = (tid >= off) ? tmp[tid - off] : 0;
      __syncthreads();
      tmp[tid] += t;
      __syncthreads();
    }
    const int carry = carry_s;
    if (i < n) offsets[i + 1] = carry + tmp[tid];
    __syncthreads();
    if (tid == 1023) carry_s = carry + tmp[1023];
    __syncthreads();
  }
}

// stores SOURCE NODE ids (not edge ids) -> node_attn has one less indirection
__global__ void scatter_edges(const int* __restrict__ dst, const int* __restrict__ src,
                              const int* __restrict__ offsets,
                              int* __restrict__ cursor, int* __restrict__ esrc, int E) {
  const int e = blockIdx.x * blockDim.x + threadIdx.x;
  if (e >= E) return;
  const int d = dst[e];
  const int pos = atomicAdd(&cursor[d], 1);
  esrc[offsets[d] + pos] = src[e];
}

// ---------------- fused per-node attention, 4-edge batches -----------------
__global__ __launch_bounds__(256) void node_attn_kernel(
    const float* __restrict__ Q, const float* __restrict__ K, const float* __restrict__ V,
    const int* __restrict__ offsets, const int* __restrict__ esrc,
    float* __restrict__ out, int N) {
  const int lane = threadIdx.x & 63;
  const int n = __builtin_amdgcn_readfirstlane((blockIdx.x * blockDim.x + threadIdx.x) >> 6);
  if (n >= N) return;
  const int beg = offsets[n], end = offsets[n + 1];
  const float2 q = *reinterpret_cast<const float2*>(Q + (size_t)n * 128 + lane * 2);
  float m = -3.4e38f, l = 0.f, ax = 0.f, ay = 0.f;
  const float scale = 0.088388347648318447f;  // 1/sqrt(128)

  int p = beg;
  for (; p + 4 <= end; p += 4) {
    const int s0 = esrc[p], s1 = esrc[p + 1], s2 = esrc[p + 2], s3 = esrc[p + 3];
    // issue all 8 row loads up front (independent; hides gather latency)
    const float2 k0 = *reinterpret_cast<const float2*>(K + (size_t)s0 * 128 + lane * 2);
    const float2 k1 = *reinterpret_cast<const float2*>(K + (size_t)s1 * 128 + lane * 2);
    const float2 k2 = *reinterpret_cast<const float2*>(K + (size_t)s2 * 128 + lane * 2);
    const float2 k3 = *reinterpret_cast<const float2*>(K + (size_t)s3 * 128 + lane * 2);
    const float2 v0 = *reinterpret_cast<const float2*>(V + (size_t)s0 * 128 + lane * 2);
    const float2 v1 = *reinterpret_cast<const float2*>(V + (size_t)s1 * 128 + lane * 2);
    const float2 v2 = *reinterpret_cast<const float2*>(V + (size_t)s2 * 128 + lane * 2);
    const float2 v3 = *reinterpret_cast<const float2*>(V + (size_t)s3 * 128 + lane * 2);
    float d0 = q.x * k0.x + q.y * k0.y;
    float d1 = q.x * k1.x + q.y * k1.y;
    float d2 = q.x * k2.x + q.y * k2.y;
    float d3 = q.x * k3.x + q.y * k3.y;
#pragma unroll
    for (int off = 32; off > 0; off >>= 1) {  // 4 interleaved reduce chains
      d0 += __shfl_xor(d0, off);
      d1 += __shfl_xor(d1, off);
      d2 += __shfl_xor(d2, off);
      d3 += __shfl_xor(d3, off);
    }
    d0 *= scale; d1 *= scale; d2 *= scale; d3 *= scale;
    const float mx = fmaxf(fmaxf(d0, d1), fmaxf(d2, d3));
    const float mnew = fmaxf(m, mx);
    const float corr = __expf(m - mnew);
    const float p0 = __expf(d0 - mnew), p1 = __expf(d1 - mnew);
    const float p2 = __expf(d2 - mnew), p3 = __expf(d3 - mnew);
    l = l * corr + (p0 + p1 + p2 + p3);
    ax = ax * corr + p0 * v0.x + p1 * v1.x + p2 * v2.x + p3 * v3.x;
    ay = ay * corr + p0 * v0.y + p1 * v1.y + p2 * v2.y + p3 * v3.y;
    m = mnew;
  }
  for (; p < end; ++p) {  // tail
    const int s = esrc[p];
    const float2 kr = *reinterpret_cast<const float2*>(K + (size_t)s * 128 + lane * 2);
    const float2 vr = *reinterpret_cast<const float2*>(V + (size_t)s * 128 + lane * 2);
    float part = q.x * kr.x + q.y * kr.y;
#pragma unroll
    for (int off = 32; off > 0; off >>= 1) part += __shfl_xor(part, off);
    const float score = part * scale;
    const float mnew = fmaxf(m, score);
    const float corr = __expf(m - mnew);
    const float pe = __expf(score - mnew);
    l = l * corr + pe;
    ax = ax * corr + pe * vr.x;
    ay = ay * corr + pe * vr.y;
    m = mnew;
  }
  const float inv = (end > beg) ? 1.f / l : 0.f;
  float2 o; o.x = ax * inv; o.y = ay * inv;
  *reinterpret_cast<float2*>(out + (size_t)n * 128 + lane * 2) = o;
}

// ---------------------------------------------------------------------------
extern "C" void kernel_launch(void* const* d_in, const int* in_sizes, int n_in,
                              void* d_out, int out_size, void* d_ws, size_t ws_size,
                              hipStream_t stream) {
  const float* edge_feat = (const float*)d_in[0];
  const float* node_feat = (const float*)d_in[1];
  const int*   src       = (const int*)d_in[2];
  const int*   dst       = (const int*)d_in[3];
  const float* Wq        = (const float*)d_in[4];
  const float* Wk        = (const float*)d_in[5];
  const float* Wv        = (const float*)d_in[6];
  const float* W1        = (const float*)d_in[7];
  const float* b1        = (const float*)d_in[8];
  const float* W2        = (const float*)d_in[9];
  const float* b2        = (const float*)d_in[10];

  const int E = in_sizes[2];            // 800000
  const int N = in_sizes[1] / D_NODE;   // 50000

  float* edge_out = (float*)d_out;
  float* node_out = (float*)d_out + (size_t)E * D_EDGE;

  char* w = (char*)d_ws;
  auto alloc = [&](size_t bytes) {
    char* p = w;
    w += (bytes + 255) & ~(size_t)255;
    return p;
  };
  float* Q    = (float*)alloc((size_t)N * 128 * sizeof(float));
  float* Km   = (float*)alloc((size_t)N * 128 * sizeof(float));
  float* Vm   = (float*)alloc((size_t)N * 128 * sizeof(float));
  int* counts = (int*)alloc((size_t)N * sizeof(int));
  int* cursor = (int*)alloc((size_t)N * sizeof(int));
  int* offs   = (int*)alloc((size_t)(N + 1) * sizeof(int));
  int* esrc   = (int*)alloc((size_t)E * sizeof(int));
  short* W1f  = (short*)alloc(8192 * sizeof(short));
  short* W2f  = (short*)alloc(8192 * sizeof(short));

  hipMemsetAsync(counts, 0, (size_t)((char*)offs - (char*)counts), stream);

  prep_weights<<<8, 256, 0, stream>>>(W1, W2, W1f, W2f);
  count_edges<<<(E + 255) / 256, 256, 0, stream>>>(dst, counts, E);
  scan_offsets<<<1, 1024, 0, stream>>>(counts, offs, N);
  scatter_edges<<<(E + 255) / 256, 256, 0, stream>>>(dst, src, offs, cursor, esrc, E);
  qkv_kernel<<<(N + 31) / 32, 256, 0, stream>>>(node_feat, Wq, Wk, Wv, Q, Km, Vm, N);
  edge_mlp_mfma<<<(E + 127) / 128, 256, 0, stream>>>(edge_feat, W1f, b1, W2f, b2, edge_out, E);
  node_attn_kernel<<<(N + 3) / 4, 256, 0, stream>>>(Q, Km, Vm, offs, esrc, node_out, N);
}

// Round 9
// 695.366 us; speedup vs baseline: 2.3275x; 1.1062x over previous
//
#include <hip/hip_runtime.h>
#include <hip/hip_bf16.h>
#include <cstdint>
#include <cstddef>

#define D_NODE 128
#define D_EDGE 64
#define D_HID  128

typedef __attribute__((ext_vector_type(8))) short bf16x8;
typedef __attribute__((ext_vector_type(4))) float f32x4;

__device__ __forceinline__ float silu_f(float x) {
  return x * __builtin_amdgcn_rcpf(1.f + __expf(-x));
}

__device__ __forceinline__ short f2bf(float f) {
  union { float f; uint32_t u; } v; v.f = f;
  uint32_t r = v.u + 0x7fff + ((v.u >> 16) & 1);  // RNE
  return (short)(r >> 16);
}

// ------------- prep: repack W1/W2 into bf16 MFMA B-fragment order ----------
__global__ void prep_weights(const float* __restrict__ W1, const float* __restrict__ W2,
                             short* __restrict__ W1f, short* __restrict__ W2f) {
  const int idx = blockIdx.x * 256 + threadIdx.x;   // 2048 threads
  if (idx < 1024) {
    const int frag = idx >> 6, lane = idx & 63;
    const int kk = frag >> 3, n = frag & 7;
    const int lg = lane >> 4, lr = lane & 15;
#pragma unroll
    for (int j = 0; j < 8; ++j) {
      const int k = kk * 32 + lg * 8 + j;
      W1f[idx * 8 + j] = f2bf(W1[k * 128 + n * 16 + lr]);
    }
  } else if (idx < 2048) {
    const int t = idx - 1024;
    const int frag = t >> 6, lane = t & 63;
    const int kk = frag >> 2, n = frag & 3;
    const int lg = lane >> 4, lr = lane & 15;
#pragma unroll
    for (int j = 0; j < 8; ++j) {
      const int k = kk * 32 + lg * 8 + j;
      W2f[t * 8 + j] = f2bf(W2[k * 64 + n * 16 + lr]);
    }
  }
}

// ------------- edge MLP via MFMA, zero barriers (unchanged) ----------------
__global__ __launch_bounds__(256) void edge_mlp_mfma(
    const float* __restrict__ ef, const short* __restrict__ W1f,
    const float* __restrict__ b1, const short* __restrict__ W2f,
    const float* __restrict__ b2, float* __restrict__ out, int E) {
  __shared__ short Hs[128 * 136];

  const int tid = threadIdx.x;
  const int e0 = blockIdx.x * 128;
  const int lane = tid & 63, wave = tid >> 6;
  const int r0 = wave * 32;
  const int lr = lane & 15, lg = lane >> 4;

  float b1v[8], b2v[4];
#pragma unroll
  for (int n = 0; n < 8; ++n) b1v[n] = b1[n * 16 + lr];
#pragma unroll
  for (int n = 0; n < 4; ++n) b2v[n] = b2[n * 16 + lr];

  // ---- GEMM1: [32 rows/wave x 128] = X(32x64) @ W1(64x128) ----
  f32x4 acc1[2][8];
#pragma unroll
  for (int m = 0; m < 2; ++m)
#pragma unroll
    for (int n = 0; n < 8; ++n) acc1[m][n] = (f32x4){0.f, 0.f, 0.f, 0.f};

#pragma unroll
  for (int kk = 0; kk < 2; ++kk) {
    bf16x8 a[2];
#pragma unroll
    for (int m = 0; m < 2; ++m) {
      const int row = e0 + r0 + m * 16 + lr;
      const float* __restrict__ xp = ef + (size_t)row * 64 + kk * 32 + lg * 8;
      float4 f0 = make_float4(0.f, 0.f, 0.f, 0.f), f1 = f0;
      if (row < E) {
        f0 = *reinterpret_cast<const float4*>(xp);
        f1 = *reinterpret_cast<const float4*>(xp + 4);
      }
      a[m][0] = f2bf(f0.x); a[m][1] = f2bf(f0.y); a[m][2] = f2bf(f0.z); a[m][3] = f2bf(f0.w);
      a[m][4] = f2bf(f1.x); a[m][5] = f2bf(f1.y); a[m][6] = f2bf(f1.z); a[m][7] = f2bf(f1.w);
    }
#pragma unroll
    for (int n = 0; n < 8; ++n) {
      const bf16x8 b = *reinterpret_cast<const bf16x8*>(W1f + (((kk << 3) + n) << 9) + (lane << 3));
      acc1[0][n] = __builtin_amdgcn_mfma_f32_16x16x32_bf16(a[0], b, acc1[0][n], 0, 0, 0);
      acc1[1][n] = __builtin_amdgcn_mfma_f32_16x16x32_bf16(a[1], b, acc1[1][n], 0, 0, 0);
    }
  }

  // ---- H = silu(acc1+b1) -> LDS ----
#pragma unroll
  for (int m = 0; m < 2; ++m)
#pragma unroll
    for (int n = 0; n < 8; ++n)
#pragma unroll
      for (int r = 0; r < 4; ++r) {
        const float hv = silu_f(acc1[m][n][r] + b1v[n]);
        Hs[(r0 + m * 16 + lg * 4 + r) * 136 + n * 16 + lr] = f2bf(hv);
      }
  // no barrier: each wave reads back only rows r0..r0+31 (its own writes)

  // ---- GEMM2: [32 x 64] = H(32x128) @ W2(128x64) ----
  f32x4 acc2[2][4];
#pragma unroll
  for (int m = 0; m < 2; ++m)
#pragma unroll
    for (int n = 0; n < 4; ++n) acc2[m][n] = (f32x4){0.f, 0.f, 0.f, 0.f};
#pragma unroll
  for (int kk = 0; kk < 4; ++kk) {
    const bf16x8 a0 = *reinterpret_cast<const bf16x8*>(&Hs[(r0 + lr) * 136 + kk * 32 + lg * 8]);
    const bf16x8 a1 = *reinterpret_cast<const bf16x8*>(&Hs[(r0 + 16 + lr) * 136 + kk * 32 + lg * 8]);
#pragma unroll
    for (int n = 0; n < 4; ++n) {
      const bf16x8 b = *reinterpret_cast<const bf16x8*>(W2f + (((kk << 2) + n) << 9) + (lane << 3));
      acc2[0][n] = __builtin_amdgcn_mfma_f32_16x16x32_bf16(a0, b, acc2[0][n], 0, 0, 0);
      acc2[1][n] = __builtin_amdgcn_mfma_f32_16x16x32_bf16(a1, b, acc2[1][n], 0, 0, 0);
    }
  }
#pragma unroll
  for (int m = 0; m < 2; ++m)
#pragma unroll
    for (int r = 0; r < 4; ++r) {
      const int row = r0 + m * 16 + lg * 4 + r;
      if (e0 + row < E) {
        float* __restrict__ op = out + (size_t)(e0 + row) * 64;
#pragma unroll
        for (int n = 0; n < 4; ++n) op[n * 16 + lr] = silu_f(acc2[m][n][r] + b2v[n]);
      }
    }
}

// ---------------- QKV projection (unchanged) -------------------------------
__global__ __launch_bounds__(256) void qkv_kernel(
    const float* __restrict__ nf, const float* __restrict__ Wq,
    const float* __restrict__ Wk, const float* __restrict__ Wv,
    float* __restrict__ Q, float* __restrict__ K, float* __restrict__ V, int N) {
  __shared__ float xs[32][D_NODE];
  const int tid = threadIdx.x;
  const int node0 = blockIdx.x * 32;
  const int nrows = min(32, N - node0);
  for (int i = tid; i < nrows * 32; i += 256) {
    const int r = i >> 5, c = (i & 31) * 4;
    float4 v = *reinterpret_cast<const float4*>(nf + (size_t)(node0 + r) * D_NODE + c);
    xs[r][c] = v.x; xs[r][c + 1] = v.y; xs[r][c + 2] = v.z; xs[r][c + 3] = v.w;
  }
  __syncthreads();
  const int wave = tid >> 6, lane = tid & 63;
  const int nn0 = wave * 8;
  float aq[8][2] = {}, ak[8][2] = {}, av[8][2] = {};
  for (int k = 0; k < D_NODE; ++k) {
    const float wq0 = Wq[(k << 7) + lane], wq1 = Wq[(k << 7) + 64 + lane];
    const float wk0 = Wk[(k << 7) + lane], wk1 = Wk[(k << 7) + 64 + lane];
    const float wv0 = Wv[(k << 7) + lane], wv1 = Wv[(k << 7) + 64 + lane];
#pragma unroll
    for (int nn = 0; nn < 8; ++nn) {
      const float x = xs[nn0 + nn][k];
      aq[nn][0] = fmaf(x, wq0, aq[nn][0]); aq[nn][1] = fmaf(x, wq1, aq[nn][1]);
      ak[nn][0] = fmaf(x, wk0, ak[nn][0]); ak[nn][1] = fmaf(x, wk1, ak[nn][1]);
      av[nn][0] = fmaf(x, wv0, av[nn][0]); av[nn][1] = fmaf(x, wv1, av[nn][1]);
    }
  }
#pragma unroll
  for (int nn = 0; nn < 8; ++nn) {
    const int n = node0 + nn0 + nn;
    if (n < N) {
      Q[(size_t)n * 128 + lane] = aq[nn][0]; Q[(size_t)n * 128 + 64 + lane] = aq[nn][1];
      K[(size_t)n * 128 + lane] = ak[nn][0]; K[(size_t)n * 128 + 64 + lane] = ak[nn][1];
      V[(size_t)n * 128 + lane] = av[nn][0]; V[(size_t)n * 128 + 64 + lane] = av[nn][1];
    }
  }
}

// ---------------- CSR build ------------------------------------------------
__global__ void count_edges(const int* __restrict__ dst, int* __restrict__ counts, int E) {
  const int e = blockIdx.x * blockDim.x + threadIdx.x;
  if (e < E) atomicAdd(&counts[dst[e]], 1);
}

// 3-pass parallel scan (replaces serial single-block scan: ~980 full-block
// barriers on one CU -> three ~5us parallel kernels)
__global__ __launch_bounds__(1024) void scan_pass1(
    const int* __restrict__ counts, int* __restrict__ offsets,
    int* __restrict__ bsums, int n) {
  __shared__ int tmp[1024];
  const int b = blockIdx.x, tid = threadIdx.x;
  const int i = b * 1024 + tid;
  tmp[tid] = (i < n) ? counts[i] : 0;
  __syncthreads();
  for (int off = 1; off < 1024; off <<= 1) {  // Hillis-Steele, 10 steps
    const int t = (tid >= off) ? tmp[tid - off] : 0;
    __syncthreads();
    tmp[tid] += t;
    __syncthreads();
  }
  if (i < n) offsets[i + 1] = tmp[tid];
  if (tid == 1023) bsums[b] = tmp[1023];
}

// nb <= 64: single-wave inclusive scan of block sums
__global__ void scan_pass2(int* __restrict__ bsums, int nb) {
  const int tid = threadIdx.x;
  int v = (tid < nb) ? bsums[tid] : 0;
#pragma unroll
  for (int off = 1; off < 64; off <<= 1) {
    const int t = __shfl_up(v, off);
    if (tid >= off) v += t;
  }
  if (tid < nb) bsums[tid] = v;
}

__global__ __launch_bounds__(1024) void scan_pass3(
    int* __restrict__ offsets, const int* __restrict__ bsums, int n) {
  const int b = blockIdx.x, tid = threadIdx.x;
  const int i = b * 1024 + tid;
  if (b > 0 && i < n) offsets[i + 1] += bsums[b - 1];
  if (b == 0 && tid == 0) offsets[0] = 0;
}

// stores SOURCE NODE ids (not edge ids) -> node_attn has one less indirection
__global__ void scatter_edges(const int* __restrict__ dst, const int* __restrict__ src,
                              const int* __restrict__ offsets,
                              int* __restrict__ cursor, int* __restrict__ esrc, int E) {
  const int e = blockIdx.x * blockDim.x + threadIdx.x;
  if (e >= E) return;
  const int d = dst[e];
  const int pos = atomicAdd(&cursor[d], 1);
  esrc[offsets[d] + pos] = src[e];
}

// ---------------- fused per-node attention, 4-edge batches (unchanged) -----
__global__ __launch_bounds__(256) void node_attn_kernel(
    const float* __restrict__ Q, const float* __restrict__ K, const float* __restrict__ V,
    const int* __restrict__ offsets, const int* __restrict__ esrc,
    float* __restrict__ out, int N) {
  const int lane = threadIdx.x & 63;
  const int n = __builtin_amdgcn_readfirstlane((blockIdx.x * blockDim.x + threadIdx.x) >> 6);
  if (n >= N) return;
  const int beg = offsets[n], end = offsets[n + 1];
  const float2 q = *reinterpret_cast<const float2*>(Q + (size_t)n * 128 + lane * 2);
  float m = -3.4e38f, l = 0.f, ax = 0.f, ay = 0.f;
  const float scale = 0.088388347648318447f;  // 1/sqrt(128)

  int p = beg;
  for (; p + 4 <= end; p += 4) {
    const int s0 = esrc[p], s1 = esrc[p + 1], s2 = esrc[p + 2], s3 = esrc[p + 3];
    const float2 k0 = *reinterpret_cast<const float2*>(K + (size_t)s0 * 128 + lane * 2);
    const float2 k1 = *reinterpret_cast<const float2*>(K + (size_t)s1 * 128 + lane * 2);
    const float2 k2 = *reinterpret_cast<const float2*>(K + (size_t)s2 * 128 + lane * 2);
    const float2 k3 = *reinterpret_cast<const float2*>(K + (size_t)s3 * 128 + lane * 2);
    const float2 v0 = *reinterpret_cast<const float2*>(V + (size_t)s0 * 128 + lane * 2);
    const float2 v1 = *reinterpret_cast<const float2*>(V + (size_t)s1 * 128 + lane * 2);
    const float2 v2 = *reinterpret_cast<const float2*>(V + (size_t)s2 * 128 + lane * 2);
    const float2 v3 = *reinterpret_cast<const float2*>(V + (size_t)s3 * 128 + lane * 2);
    float d0 = q.x * k0.x + q.y * k0.y;
    float d1 = q.x * k1.x + q.y * k1.y;
    float d2 = q.x * k2.x + q.y * k2.y;
    float d3 = q.x * k3.x + q.y * k3.y;
#pragma unroll
    for (int off = 32; off > 0; off >>= 1) {
      d0 += __shfl_xor(d0, off);
      d1 += __shfl_xor(d1, off);
      d2 += __shfl_xor(d2, off);
      d3 += __shfl_xor(d3, off);
    }
    d0 *= scale; d1 *= scale; d2 *= scale; d3 *= scale;
    const float mx = fmaxf(fmaxf(d0, d1), fmaxf(d2, d3));
    const float mnew = fmaxf(m, mx);
    const float corr = __expf(m - mnew);
    const float p0 = __expf(d0 - mnew), p1 = __expf(d1 - mnew);
    const float p2 = __expf(d2 - mnew), p3 = __expf(d3 - mnew);
    l = l * corr + (p0 + p1 + p2 + p3);
    ax = ax * corr + p0 * v0.x + p1 * v1.x + p2 * v2.x + p3 * v3.x;
    ay = ay * corr + p0 * v0.y + p1 * v1.y + p2 * v2.y + p3 * v3.y;
    m = mnew;
  }
  for (; p < end; ++p) {  // tail
    const int s = esrc[p];
    const float2 kr = *reinterpret_cast<const float2*>(K + (size_t)s * 128 + lane * 2);
    const float2 vr = *reinterpret_cast<const float2*>(V + (size_t)s * 128 + lane * 2);
    float part = q.x * kr.x + q.y * kr.y;
#pragma unroll
    for (int off = 32; off > 0; off >>= 1) part += __shfl_xor(part, off);
    const float score = part * scale;
    const float mnew = fmaxf(m, score);
    const float corr = __expf(m - mnew);
    const float pe = __expf(score - mnew);
    l = l * corr + pe;
    ax = ax * corr + pe * vr.x;
    ay = ay * corr + pe * vr.y;
    m = mnew;
  }
  const float inv = (end > beg) ? 1.f / l : 0.f;
  float2 o; o.x = ax * inv; o.y = ay * inv;
  *reinterpret_cast<float2*>(out + (size_t)n * 128 + lane * 2) = o;
}

// ---------------------------------------------------------------------------
extern "C" void kernel_launch(void* const* d_in, const int* in_sizes, int n_in,
                              void* d_out, int out_size, void* d_ws, size_t ws_size,
                              hipStream_t stream) {
  const float* edge_feat = (const float*)d_in[0];
  const float* node_feat = (const float*)d_in[1];
  const int*   src       = (const int*)d_in[2];
  const int*   dst       = (const int*)d_in[3];
  const float* Wq        = (const float*)d_in[4];
  const float* Wk        = (const float*)d_in[5];
  const float* Wv        = (const float*)d_in[6];
  const float* W1        = (const float*)d_in[7];
  const float* b1        = (const float*)d_in[8];
  const float* W2        = (const float*)d_in[9];
  const float* b2        = (const float*)d_in[10];

  const int E = in_sizes[2];            // 800000
  const int N = in_sizes[1] / D_NODE;   // 50000

  float* edge_out = (float*)d_out;
  float* node_out = (float*)d_out + (size_t)E * D_EDGE;

  char* w = (char*)d_ws;
  auto alloc = [&](size_t bytes) {
    char* p = w;
    w += (bytes + 255) & ~(size_t)255;
    return p;
  };
  float* Q    = (float*)alloc((size_t)N * 128 * sizeof(float));
  float* Km   = (float*)alloc((size_t)N * 128 * sizeof(float));
  float* Vm   = (float*)alloc((size_t)N * 128 * sizeof(float));
  int* counts = (int*)alloc((size_t)N * sizeof(int));
  int* cursor = (int*)alloc((size_t)N * sizeof(int));
  int* offs   = (int*)alloc((size_t)(N + 1) * sizeof(int));
  int* esrc   = (int*)alloc((size_t)E * sizeof(int));
  short* W1f  = (short*)alloc(8192 * sizeof(short));
  short* W2f  = (short*)alloc(8192 * sizeof(short));
  int* bsums  = (int*)alloc(64 * sizeof(int));

  hipMemsetAsync(counts, 0, (size_t)((char*)offs - (char*)counts), stream);

  const int nb = (N + 1023) / 1024;     // 49 blocks
  prep_weights<<<8, 256, 0, stream>>>(W1, W2, W1f, W2f);
  count_edges<<<(E + 255) / 256, 256, 0, stream>>>(dst, counts, E);
  scan_pass1<<<nb, 1024, 0, stream>>>(counts, offs, bsums, N);
  scan_pass2<<<1, 64, 0, stream>>>(bsums, nb);
  scan_pass3<<<nb, 1024, 0, stream>>>(offs, bsums, N);
  scatter_edges<<<(E + 255) / 256, 256, 0, stream>>>(dst, src, offs, cursor, esrc, E);
  qkv_kernel<<<(N + 31) / 32, 256, 0, stream>>>(node_feat, Wq, Wk, Wv, Q, Km, Vm, N);
  edge_mlp_mfma<<<(E + 127) / 128, 256, 0, stream>>>(edge_feat, W1f, b1, W2f, b2, edge_out, E);
  node_attn_kernel<<<(N + 3) / 4, 256, 0, stream>>>(Q, Km, Vm, offs, esrc, node_out, N);
}

// Round 10
// 636.360 us; speedup vs baseline: 2.5434x; 1.0927x over previous
//
#include <hip/hip_runtime.h>
#include <hip/hip_bf16.h>
#include <cstdint>
#include <cstddef>

#define D_NODE 128
#define D_EDGE 64
#define D_HID  128

typedef __attribute__((ext_vector_type(8))) short bf16x8;
typedef __attribute__((ext_vector_type(4))) float f32x4;

__device__ __forceinline__ float silu_f(float x) {
  return x * __builtin_amdgcn_rcpf(1.f + __expf(-x));
}

__device__ __forceinline__ short f2bf(float f) {
  union { float f; uint32_t u; } v; v.f = f;
  uint32_t r = v.u + 0x7fff + ((v.u >> 16) & 1);  // RNE
  return (short)(r >> 16);
}

__device__ __forceinline__ float bf2f(uint32_t lo16) {
  union { uint32_t u; float f; } v; v.u = lo16 << 16; return v.f;
}

__device__ __forceinline__ uint32_t packkv(float k, float v) {
  return (uint32_t)(uint16_t)f2bf(k) | ((uint32_t)(uint16_t)f2bf(v) << 16);
}

// ------------- prep: repack W1/W2 into bf16 MFMA B-fragment order ----------
__global__ void prep_weights(const float* __restrict__ W1, const float* __restrict__ W2,
                             short* __restrict__ W1f, short* __restrict__ W2f) {
  const int idx = blockIdx.x * 256 + threadIdx.x;   // 2048 threads
  if (idx < 1024) {
    const int frag = idx >> 6, lane = idx & 63;
    const int kk = frag >> 3, n = frag & 7;
    const int lg = lane >> 4, lr = lane & 15;
#pragma unroll
    for (int j = 0; j < 8; ++j) {
      const int k = kk * 32 + lg * 8 + j;
      W1f[idx * 8 + j] = f2bf(W1[k * 128 + n * 16 + lr]);
    }
  } else if (idx < 2048) {
    const int t = idx - 1024;
    const int frag = t >> 6, lane = t & 63;
    const int kk = frag >> 2, n = frag & 3;
    const int lg = lane >> 4, lr = lane & 15;
#pragma unroll
    for (int j = 0; j < 8; ++j) {
      const int k = kk * 32 + lg * 8 + j;
      W2f[t * 8 + j] = f2bf(W2[k * 64 + n * 16 + lr]);
    }
  }
}

// ------------- edge MLP via MFMA, zero barriers (unchanged) ----------------
__global__ __launch_bounds__(256) void edge_mlp_mfma(
    const float* __restrict__ ef, const short* __restrict__ W1f,
    const float* __restrict__ b1, const short* __restrict__ W2f,
    const float* __restrict__ b2, float* __restrict__ out, int E) {
  __shared__ short Hs[128 * 136];

  const int tid = threadIdx.x;
  const int e0 = blockIdx.x * 128;
  const int lane = tid & 63, wave = tid >> 6;
  const int r0 = wave * 32;
  const int lr = lane & 15, lg = lane >> 4;

  float b1v[8], b2v[4];
#pragma unroll
  for (int n = 0; n < 8; ++n) b1v[n] = b1[n * 16 + lr];
#pragma unroll
  for (int n = 0; n < 4; ++n) b2v[n] = b2[n * 16 + lr];

  // ---- GEMM1: [32 rows/wave x 128] = X(32x64) @ W1(64x128) ----
  f32x4 acc1[2][8];
#pragma unroll
  for (int m = 0; m < 2; ++m)
#pragma unroll
    for (int n = 0; n < 8; ++n) acc1[m][n] = (f32x4){0.f, 0.f, 0.f, 0.f};

#pragma unroll
  for (int kk = 0; kk < 2; ++kk) {
    bf16x8 a[2];
#pragma unroll
    for (int m = 0; m < 2; ++m) {
      const int row = e0 + r0 + m * 16 + lr;
      const float* __restrict__ xp = ef + (size_t)row * 64 + kk * 32 + lg * 8;
      float4 f0 = make_float4(0.f, 0.f, 0.f, 0.f), f1 = f0;
      if (row < E) {
        f0 = *reinterpret_cast<const float4*>(xp);
        f1 = *reinterpret_cast<const float4*>(xp + 4);
      }
      a[m][0] = f2bf(f0.x); a[m][1] = f2bf(f0.y); a[m][2] = f2bf(f0.z); a[m][3] = f2bf(f0.w);
      a[m][4] = f2bf(f1.x); a[m][5] = f2bf(f1.y); a[m][6] = f2bf(f1.z); a[m][7] = f2bf(f1.w);
    }
#pragma unroll
    for (int n = 0; n < 8; ++n) {
      const bf16x8 b = *reinterpret_cast<const bf16x8*>(W1f + (((kk << 3) + n) << 9) + (lane << 3));
      acc1[0][n] = __builtin_amdgcn_mfma_f32_16x16x32_bf16(a[0], b, acc1[0][n], 0, 0, 0);
      acc1[1][n] = __builtin_amdgcn_mfma_f32_16x16x32_bf16(a[1], b, acc1[1][n], 0, 0, 0);
    }
  }

  // ---- H = silu(acc1+b1) -> LDS ----
#pragma unroll
  for (int m = 0; m < 2; ++m)
#pragma unroll
    for (int n = 0; n < 8; ++n)
#pragma unroll
      for (int r = 0; r < 4; ++r) {
        const float hv = silu_f(acc1[m][n][r] + b1v[n]);
        Hs[(r0 + m * 16 + lg * 4 + r) * 136 + n * 16 + lr] = f2bf(hv);
      }
  // no barrier: each wave reads back only rows r0..r0+31 (its own writes)

  // ---- GEMM2: [32 x 64] = H(32x128) @ W2(128x64) ----
  f32x4 acc2[2][4];
#pragma unroll
  for (int m = 0; m < 2; ++m)
#pragma unroll
    for (int n = 0; n < 4; ++n) acc2[m][n] = (f32x4){0.f, 0.f, 0.f, 0.f};
#pragma unroll
  for (int kk = 0; kk < 4; ++kk) {
    const bf16x8 a0 = *reinterpret_cast<const bf16x8*>(&Hs[(r0 + lr) * 136 + kk * 32 + lg * 8]);
    const bf16x8 a1 = *reinterpret_cast<const bf16x8*>(&Hs[(r0 + 16 + lr) * 136 + kk * 32 + lg * 8]);
#pragma unroll
    for (int n = 0; n < 4; ++n) {
      const bf16x8 b = *reinterpret_cast<const bf16x8*>(W2f + (((kk << 2) + n) << 9) + (lane << 3));
      acc2[0][n] = __builtin_amdgcn_mfma_f32_16x16x32_bf16(a0, b, acc2[0][n], 0, 0, 0);
      acc2[1][n] = __builtin_amdgcn_mfma_f32_16x16x32_bf16(a1, b, acc2[1][n], 0, 0, 0);
    }
  }
#pragma unroll
  for (int m = 0; m < 2; ++m)
#pragma unroll
    for (int r = 0; r < 4; ++r) {
      const int row = r0 + m * 16 + lg * 4 + r;
      if (e0 + row < E) {
        float* __restrict__ op = out + (size_t)(e0 + row) * 64;
#pragma unroll
        for (int n = 0; n < 4; ++n) op[n * 16 + lr] = silu_f(acc2[m][n][r] + b2v[n]);
      }
    }
}

// ---------------- QKV projection: Q fp32, K/V packed bf16 ------------------
__global__ __launch_bounds__(256) void qkv_kernel(
    const float* __restrict__ nf, const float* __restrict__ Wq,
    const float* __restrict__ Wk, const float* __restrict__ Wv,
    float* __restrict__ Q, uint32_t* __restrict__ KV, int N) {
  __shared__ float xs[32][D_NODE];
  const int tid = threadIdx.x;
  const int node0 = blockIdx.x * 32;
  const int nrows = min(32, N - node0);
  for (int i = tid; i < nrows * 32; i += 256) {
    const int r = i >> 5, c = (i & 31) * 4;
    float4 v = *reinterpret_cast<const float4*>(nf + (size_t)(node0 + r) * D_NODE + c);
    xs[r][c] = v.x; xs[r][c + 1] = v.y; xs[r][c + 2] = v.z; xs[r][c + 3] = v.w;
  }
  __syncthreads();
  const int wave = tid >> 6, lane = tid & 63;
  const int nn0 = wave * 8;
  float aq[8][2] = {}, ak[8][2] = {}, av[8][2] = {};
  for (int k = 0; k < D_NODE; ++k) {
    const float wq0 = Wq[(k << 7) + lane], wq1 = Wq[(k << 7) + 64 + lane];
    const float wk0 = Wk[(k << 7) + lane], wk1 = Wk[(k << 7) + 64 + lane];
    const float wv0 = Wv[(k << 7) + lane], wv1 = Wv[(k << 7) + 64 + lane];
#pragma unroll
    for (int nn = 0; nn < 8; ++nn) {
      const float x = xs[nn0 + nn][k];
      aq[nn][0] = fmaf(x, wq0, aq[nn][0]); aq[nn][1] = fmaf(x, wq1, aq[nn][1]);
      ak[nn][0] = fmaf(x, wk0, ak[nn][0]); ak[nn][1] = fmaf(x, wk1, ak[nn][1]);
      av[nn][0] = fmaf(x, wv0, av[nn][0]); av[nn][1] = fmaf(x, wv1, av[nn][1]);
    }
  }
#pragma unroll
  for (int nn = 0; nn < 8; ++nn) {
    const int n = node0 + nn0 + nn;
    if (n < N) {
      Q[(size_t)n * 128 + lane] = aq[nn][0]; Q[(size_t)n * 128 + 64 + lane] = aq[nn][1];
      KV[(size_t)n * 128 + lane]      = packkv(ak[nn][0], av[nn][0]);
      KV[(size_t)n * 128 + 64 + lane] = packkv(ak[nn][1], av[nn][1]);
    }
  }
}

// ---------------- CSR build ------------------------------------------------
__global__ void count_edges(const int* __restrict__ dst, int* __restrict__ counts, int E) {
  const int e = blockIdx.x * blockDim.x + threadIdx.x;
  if (e < E) atomicAdd(&counts[dst[e]], 1);
}

__global__ __launch_bounds__(1024) void scan_pass1(
    const int* __restrict__ counts, int* __restrict__ offsets,
    int* __restrict__ bsums, int n) {
  __shared__ int tmp[1024];
  const int b = blockIdx.x, tid = threadIdx.x;
  const int i = b * 1024 + tid;
  tmp[tid] = (i < n) ? counts[i] : 0;
  __syncthreads();
  for (int off = 1; off < 1024; off <<= 1) {
    const int t = (tid >= off) ? tmp[tid - off] : 0;
    __syncthreads();
    tmp[tid] += t;
    __syncthreads();
  }
  if (i < n) offsets[i + 1] = tmp[tid];
  if (tid == 1023) bsums[b] = tmp[1023];
}

__global__ void scan_pass2(int* __restrict__ bsums, int nb) {
  const int tid = threadIdx.x;
  int v = (tid < nb) ? bsums[tid] : 0;
#pragma unroll
  for (int off = 1; off < 64; off <<= 1) {
    const int t = __shfl_up(v, off);
    if (tid >= off) v += t;
  }
  if (tid < nb) bsums[tid] = v;
}

__global__ __launch_bounds__(1024) void scan_pass3(
    int* __restrict__ offsets, const int* __restrict__ bsums, int n) {
  const int b = blockIdx.x, tid = threadIdx.x;
  const int i = b * 1024 + tid;
  if (b > 0 && i < n) offsets[i + 1] += bsums[b - 1];
  if (b == 0 && tid == 0) offsets[0] = 0;
}

__global__ void scatter_edges(const int* __restrict__ dst, const int* __restrict__ src,
                              const int* __restrict__ offsets,
                              int* __restrict__ cursor, int* __restrict__ esrc, int E) {
  const int e = blockIdx.x * blockDim.x + threadIdx.x;
  if (e >= E) return;
  const int d = dst[e];
  const int pos = atomicAdd(&cursor[d], 1);
  esrc[offsets[d] + pos] = src[e];
}

// ---------------- fused per-node attention, packed bf16 KV -----------------
// One uint2 load per lane per edge delivers K and V for both owned columns.
__global__ __launch_bounds__(256) void node_attn_kernel(
    const float* __restrict__ Q, const uint32_t* __restrict__ KV,
    const int* __restrict__ offsets, const int* __restrict__ esrc,
    float* __restrict__ out, int N) {
  const int lane = threadIdx.x & 63;
  const int n = __builtin_amdgcn_readfirstlane((blockIdx.x * blockDim.x + threadIdx.x) >> 6);
  if (n >= N) return;
  const int beg = offsets[n], end = offsets[n + 1];
  const float scale = 0.088388347648318447f;  // 1/sqrt(128)
  float2 q = *reinterpret_cast<const float2*>(Q + (size_t)n * 128 + lane * 2);
  q.x *= scale; q.y *= scale;                 // fold scale into Q
  float m = -3.4e38f, l = 0.f, ax = 0.f, ay = 0.f;

  int p = beg;
  for (; p + 4 <= end; p += 4) {
    const int s0 = esrc[p], s1 = esrc[p + 1], s2 = esrc[p + 2], s3 = esrc[p + 3];
    const uint2 c0 = *reinterpret_cast<const uint2*>(KV + (size_t)s0 * 128 + lane * 2);
    const uint2 c1 = *reinterpret_cast<const uint2*>(KV + (size_t)s1 * 128 + lane * 2);
    const uint2 c2 = *reinterpret_cast<const uint2*>(KV + (size_t)s2 * 128 + lane * 2);
    const uint2 c3 = *reinterpret_cast<const uint2*>(KV + (size_t)s3 * 128 + lane * 2);
    float d0 = q.x * bf2f(c0.x & 0xffff) + q.y * bf2f(c0.y & 0xffff);
    float d1 = q.x * bf2f(c1.x & 0xffff) + q.y * bf2f(c1.y & 0xffff);
    float d2 = q.x * bf2f(c2.x & 0xffff) + q.y * bf2f(c2.y & 0xffff);
    float d3 = q.x * bf2f(c3.x & 0xffff) + q.y * bf2f(c3.y & 0xffff);
#pragma unroll
    for (int off = 32; off > 0; off >>= 1) {
      d0 += __shfl_xor(d0, off);
      d1 += __shfl_xor(d1, off);
      d2 += __shfl_xor(d2, off);
      d3 += __shfl_xor(d3, off);
    }
    const float mx = fmaxf(fmaxf(d0, d1), fmaxf(d2, d3));
    const float mnew = fmaxf(m, mx);
    const float corr = __expf(m - mnew);
    const float p0 = __expf(d0 - mnew), p1 = __expf(d1 - mnew);
    const float p2 = __expf(d2 - mnew), p3 = __expf(d3 - mnew);
    l = l * corr + (p0 + p1 + p2 + p3);
    ax = ax * corr + p0 * bf2f(c0.x >> 16) + p1 * bf2f(c1.x >> 16)
                   + p2 * bf2f(c2.x >> 16) + p3 * bf2f(c3.x >> 16);
    ay = ay * corr + p0 * bf2f(c0.y >> 16) + p1 * bf2f(c1.y >> 16)
                   + p2 * bf2f(c2.y >> 16) + p3 * bf2f(c3.y >> 16);
    m = mnew;
  }
  for (; p < end; ++p) {  // tail
    const int s = esrc[p];
    const uint2 c = *reinterpret_cast<const uint2*>(KV + (size_t)s * 128 + lane * 2);
    float part = q.x * bf2f(c.x & 0xffff) + q.y * bf2f(c.y & 0xffff);
#pragma unroll
    for (int off = 32; off > 0; off >>= 1) part += __shfl_xor(part, off);
    const float mnew = fmaxf(m, part);
    const float corr = __expf(m - mnew);
    const float pe = __expf(part - mnew);
    l = l * corr + pe;
    ax = ax * corr + pe * bf2f(c.x >> 16);
    ay = ay * corr + pe * bf2f(c.y >> 16);
    m = mnew;
  }
  const float inv = (end > beg) ? 1.f / l : 0.f;
  float2 o; o.x = ax * inv; o.y = ay * inv;
  *reinterpret_cast<float2*>(out + (size_t)n * 128 + lane * 2) = o;
}

// ---------------------------------------------------------------------------
extern "C" void kernel_launch(void* const* d_in, const int* in_sizes, int n_in,
                              void* d_out, int out_size, void* d_ws, size_t ws_size,
                              hipStream_t stream) {
  const float* edge_feat = (const float*)d_in[0];
  const float* node_feat = (const float*)d_in[1];
  const int*   src       = (const int*)d_in[2];
  const int*   dst       = (const int*)d_in[3];
  const float* Wq        = (const float*)d_in[4];
  const float* Wk        = (const float*)d_in[5];
  const float* Wv        = (const float*)d_in[6];
  const float* W1        = (const float*)d_in[7];
  const float* b1        = (const float*)d_in[8];
  const float* W2        = (const float*)d_in[9];
  const float* b2        = (const float*)d_in[10];

  const int E = in_sizes[2];            // 800000
  const int N = in_sizes[1] / D_NODE;   // 50000

  float* edge_out = (float*)d_out;
  float* node_out = (float*)d_out + (size_t)E * D_EDGE;

  char* w = (char*)d_ws;
  auto alloc = [&](size_t bytes) {
    char* p = w;
    w += (bytes + 255) & ~(size_t)255;
    return p;
  };
  float*    Q   = (float*)alloc((size_t)N * 128 * sizeof(float));
  uint32_t* KV  = (uint32_t*)alloc((size_t)N * 128 * sizeof(uint32_t));
  int* counts = (int*)alloc((size_t)N * sizeof(int));
  int* cursor = (int*)alloc((size_t)N * sizeof(int));
  int* offs   = (int*)alloc((size_t)(N + 1) * sizeof(int));
  int* esrc   = (int*)alloc((size_t)E * sizeof(int));
  short* W1f  = (short*)alloc(8192 * sizeof(short));
  short* W2f  = (short*)alloc(8192 * sizeof(short));
  int* bsums  = (int*)alloc(64 * sizeof(int));

  hipMemsetAsync(counts, 0, (size_t)((char*)offs - (char*)counts), stream);

  const int nb = (N + 1023) / 1024;     // 49 blocks
  prep_weights<<<8, 256, 0, stream>>>(W1, W2, W1f, W2f);
  count_edges<<<(E + 255) / 256, 256, 0, stream>>>(dst, counts, E);
  scan_pass1<<<nb, 1024, 0, stream>>>(counts, offs, bsums, N);
  scan_pass2<<<1, 64, 0, stream>>>(bsums, nb);
  scan_pass3<<<nb, 1024, 0, stream>>>(offs, bsums, N);
  scatter_edges<<<(E + 255) / 256, 256, 0, stream>>>(dst, src, offs, cursor, esrc, E);
  qkv_kernel<<<(N + 31) / 32, 256, 0, stream>>>(node_feat, Wq, Wk, Wv, Q, KV, N);
  edge_mlp_mfma<<<(E + 127) / 128, 256, 0, stream>>>(edge_feat, W1f, b1, W2f, b2, edge_out, E);
  node_attn_kernel<<<(N + 3) / 4, 256, 0, stream>>>(Q, KV, offs, esrc, node_out, N);
}